// Round 2
// baseline (245.116 us; speedup 1.0000x reference)
//
#include <hip/hip_runtime.h>

#define N_ATOMS 50000
#define N_PAIRS 1600000
#define FDIM 128

// ---------------------------------------------------------------------------
// Kernel A: v = x @ W^T   (v[m][f] = sum_k x[m][k] * W[f][k])
// block = 256 threads, 32 rows/block, full 128 features, k in 2 chunks of 64.
// Thread t: rg = t&7 -> rows 4*rg..4*rg+3 ; fg = t>>3 -> feats 4*fg..4*fg+3.
// LDS: Ws[f][kc] stride 65, Xs[kc][r] stride 36 (float4-aligned reads).
// ---------------------------------------------------------------------------
__global__ __launch_bounds__(256) void gemm_xwt(const float* __restrict__ x,
                                                const float* __restrict__ W,
                                                float* __restrict__ v) {
    __shared__ __align__(16) float Ws[128 * 65];
    __shared__ __align__(16) float Xs[64 * 36];

    const int t  = threadIdx.x;
    const int rg = t & 7;    // row group
    const int fg = t >> 3;   // feature group (0..31)
    const int m0 = blockIdx.x * 32;

    float acc[4][4];
#pragma unroll
    for (int a = 0; a < 4; ++a)
#pragma unroll
        for (int b = 0; b < 4; ++b) acc[a][b] = 0.f;

    for (int k0 = 0; k0 < FDIM; k0 += 64) {
        __syncthreads();
        // stage W chunk: 128 f x 64 k  (2048 float4, 8 per thread)
#pragma unroll
        for (int u = 0; u < 8; ++u) {
            int id = t + 256 * u;
            int f  = id >> 4;     // 0..127
            int kq = id & 15;     // 0..15
            const float4 w4 = *(const float4*)(W + f * FDIM + k0 + 4 * kq);
            float* d = &Ws[f * 65 + 4 * kq];
            d[0] = w4.x; d[1] = w4.y; d[2] = w4.z; d[3] = w4.w;
        }
        // stage X chunk: 32 rows x 64 k (512 float4, 2 per thread), transposed
#pragma unroll
        for (int u = 0; u < 2; ++u) {
            int id = t + 256 * u;
            int r  = id >> 4;     // 0..31
            int kq = id & 15;
            float4 x4 = make_float4(0.f, 0.f, 0.f, 0.f);
            int row = m0 + r;
            if (row < N_ATOMS)
                x4 = *(const float4*)(x + (long)row * FDIM + k0 + 4 * kq);
            Xs[(4 * kq + 0) * 36 + r] = x4.x;
            Xs[(4 * kq + 1) * 36 + r] = x4.y;
            Xs[(4 * kq + 2) * 36 + r] = x4.z;
            Xs[(4 * kq + 3) * 36 + r] = x4.w;
        }
        __syncthreads();

#pragma unroll 8
        for (int kc = 0; kc < 64; ++kc) {
            const float4 xv = *(const float4*)&Xs[kc * 36 + 4 * rg];
            const float w0 = Ws[(4 * fg + 0) * 65 + kc];
            const float w1 = Ws[(4 * fg + 1) * 65 + kc];
            const float w2 = Ws[(4 * fg + 2) * 65 + kc];
            const float w3 = Ws[(4 * fg + 3) * 65 + kc];
            acc[0][0] += xv.x * w0; acc[0][1] += xv.x * w1; acc[0][2] += xv.x * w2; acc[0][3] += xv.x * w3;
            acc[1][0] += xv.y * w0; acc[1][1] += xv.y * w1; acc[1][2] += xv.y * w2; acc[1][3] += xv.y * w3;
            acc[2][0] += xv.z * w0; acc[2][1] += xv.z * w1; acc[2][2] += xv.z * w2; acc[2][3] += xv.z * w3;
            acc[3][0] += xv.w * w0; acc[3][1] += xv.w * w1; acc[3][2] += xv.w * w2; acc[3][3] += xv.w * w3;
        }
    }

#pragma unroll
    for (int ri = 0; ri < 4; ++ri) {
        int row = m0 + 4 * rg + ri;
        if (row < N_ATOMS) {
            float4 o = make_float4(acc[ri][0], acc[ri][1], acc[ri][2], acc[ri][3]);
            *(float4*)(v + (long)row * FDIM + 4 * fg) = o;
        }
    }
}

// ---------------------------------------------------------------------------
// Kernel B: y[idx_i[p], :] += alpha[p] * v[idx_j[p], :]
// One wave per 64 consecutive pairs. idx_i is sorted -> register
// run-accumulation, flush on i-change via device-scope atomicAdd.
// Lane l holds features 2l, 2l+1 (float2 -> 512B coalesced row read).
// Per-pair scalars lane-preloaded then __shfl-broadcast -> flush branch is
// wave-uniform (no divergence).
// NOTE: harness delivers integer inputs as int32 (not the reference's int64).
// ---------------------------------------------------------------------------
__global__ __launch_bounds__(256) void scatter_agg(const float* __restrict__ v,
                                                   const float* __restrict__ alpha,
                                                   const int* __restrict__ idx_i,
                                                   const int* __restrict__ idx_j,
                                                   float* __restrict__ y) {
    const int lane = threadIdx.x & 63;
    const long wave = (long)((blockIdx.x * (long)blockDim.x + threadIdx.x) >> 6);
    const long p0 = wave * 64;
    if (p0 >= N_PAIRS) return;

    const int   my_i = idx_i[p0 + lane];
    const int   my_j = idx_j[p0 + lane];
    const float my_a = alpha[p0 + lane];

    float2 acc = make_float2(0.f, 0.f);
    int cur = __shfl(my_i, 0);

#pragma unroll 8
    for (int u = 0; u < 64; ++u) {
        const int   i = __shfl(my_i, u);
        const int   j = __shfl(my_j, u);
        const float a = __shfl(my_a, u);
        const float2 vv = *(const float2*)(v + (long)j * FDIM + 2 * lane);
        if (i != cur) {
            atomicAdd(&y[(long)cur * FDIM + 2 * lane + 0], acc.x);
            atomicAdd(&y[(long)cur * FDIM + 2 * lane + 1], acc.y);
            acc = make_float2(0.f, 0.f);
            cur = i;
        }
        acc.x += a * vv.x;
        acc.y += a * vv.y;
    }
    atomicAdd(&y[(long)cur * FDIM + 2 * lane + 0], acc.x);
    atomicAdd(&y[(long)cur * FDIM + 2 * lane + 1], acc.y);
}

extern "C" void kernel_launch(void* const* d_in, const int* in_sizes, int n_in,
                              void* d_out, int out_size, void* d_ws, size_t ws_size,
                              hipStream_t stream) {
    const float* x     = (const float*)d_in[0];
    const float* alpha = (const float*)d_in[1];
    const int*   idx_i = (const int*)d_in[2];   // int32 per harness contract
    const int*   idx_j = (const int*)d_in[3];   // int32 per harness contract
    const float* W     = (const float*)d_in[4];
    float* y = (float*)d_out;
    float* v = (float*)d_ws;   // 50000*128*4 = 25.6 MB scratch

    // harness poisons d_out with 0xAA before every timed launch -> zero it
    hipMemsetAsync(d_out, 0, (size_t)out_size * sizeof(float), stream);

    gemm_xwt<<<(N_ATOMS + 31) / 32, 256, 0, stream>>>(x, W, v);

    const int waves  = N_PAIRS / 64;           // 25000
    const int blocks = waves / 4;              // 6250 blocks of 4 waves
    scatter_agg<<<blocks, 256, 0, stream>>>(v, alpha, idx_i, idx_j, y);
}

// Round 3
// 157.245 us; speedup vs baseline: 1.5588x; 1.5588x over previous
//
#include <hip/hip_runtime.h>

#define N_ATOMS 50000
#define N_PAIRS 1600000
#define FDIM 128

typedef short short8 __attribute__((ext_vector_type(8)));
typedef float floatx4 __attribute__((ext_vector_type(4)));

// fp32 -> bf16 with round-to-nearest-even
__device__ inline ushort f2bf(float f) {
    union { float f; unsigned u; } v; v.f = f;
    unsigned lsb = (v.u >> 16) & 1u;
    return (ushort)((v.u + 0x7fffu + lsb) >> 16);
}

// ---------------------------------------------------------------------------
// K1: rowptr[i] = lower_bound(idx_i, i)  for i in [0, N_ATOMS]
// idx_i is sorted (reference sorts it). 21-step binary search, L2-resident.
// ---------------------------------------------------------------------------
__global__ __launch_bounds__(256) void build_rowptr(const int* __restrict__ idx_i,
                                                    int* __restrict__ rowptr) {
    int i = blockIdx.x * 256 + threadIdx.x;
    if (i > N_ATOMS) return;
    int lo = 0, hi = N_PAIRS;
    while (lo < hi) {
        int mid = (lo + hi) >> 1;
        if (idx_i[mid] < i) lo = mid + 1; else hi = mid;
    }
    rowptr[i] = lo;
}

// ---------------------------------------------------------------------------
// K2: v = bf16(x @ W^T) via mfma_f32_16x16x32_bf16.
// Block 256 = 4 waves; wave handles 16 rows x all 128 features.
// W staged in LDS as bf16, stride 136 shorts (stride_dw/4 = 17 odd ->
// b128 reads land 2-way on bank-quads = free per m136).
// A-frag: lane reads x[m0+(lane&15)][32*kc + 8*(lane>>4) + 0..7] (verified
// A[m=lane&15][k=quad*8+j] layout). C/D: col=lane&15, row=4*quad+reg.
// ---------------------------------------------------------------------------
__global__ __launch_bounds__(256) void gemm_xwt_bf16(const float* __restrict__ x,
                                                     const float* __restrict__ W,
                                                     ushort* __restrict__ v) {
    __shared__ ushort Wsh[128 * 136];
    const int t = threadIdx.x;

    // stage W (128x128 fp32 -> bf16): 4096 float4, 16 per thread
#pragma unroll
    for (int u = 0; u < 16; ++u) {
        int id = t + 256 * u;          // float4 index
        int f  = id >> 5;              // 32 float4 per row
        int k4 = (id & 31) * 4;
        const float4 w4 = *(const float4*)(W + f * FDIM + k4);
        ushort* d = &Wsh[f * 136 + k4];
        d[0] = f2bf(w4.x); d[1] = f2bf(w4.y); d[2] = f2bf(w4.z); d[3] = f2bf(w4.w);
    }
    __syncthreads();

    const int lane = t & 63;
    const int wv   = t >> 6;
    const int mrow = lane & 15;
    const int q    = lane >> 4;
    const int mw   = blockIdx.x * 64 + wv * 16;   // wave's row base

    // A fragments for the 4 k-chunks (convert fp32->bf16 in registers)
    int row = mw + mrow;
    if (row >= N_ATOMS) row = N_ATOMS - 1;        // clamp; stores are guarded
    const float* xr = x + (long)row * FDIM + 8 * q;
    short8 a[4];
#pragma unroll
    for (int kc = 0; kc < 4; ++kc) {
        const float4 lo4 = *(const float4*)(xr + 32 * kc);
        const float4 hi4 = *(const float4*)(xr + 32 * kc + 4);
        short8 af;
        af[0] = f2bf(lo4.x); af[1] = f2bf(lo4.y); af[2] = f2bf(lo4.z); af[3] = f2bf(lo4.w);
        af[4] = f2bf(hi4.x); af[5] = f2bf(hi4.y); af[6] = f2bf(hi4.z); af[7] = f2bf(hi4.w);
        a[kc] = af;
    }

    floatx4 acc[8];
#pragma unroll
    for (int f = 0; f < 8; ++f) acc[f] = (floatx4)(0.f);

#pragma unroll
    for (int f = 0; f < 8; ++f) {
        const ushort* wr = &Wsh[(16 * f + mrow) * 136 + 8 * q];
#pragma unroll
        for (int kc = 0; kc < 4; ++kc) {
            const short8 bf = *(const short8*)(wr + 32 * kc);
            acc[f] = __builtin_amdgcn_mfma_f32_16x16x32_bf16(a[kc], bf, acc[f], 0, 0, 0);
        }
    }

    // epilogue: D[row=4q+r][col=16f+mrow] -> bf16 store
#pragma unroll
    for (int f = 0; f < 8; ++f) {
#pragma unroll
        for (int r = 0; r < 4; ++r) {
            const int orow = mw + 4 * q + r;
            if (orow < N_ATOMS)
                v[(long)orow * FDIM + 16 * f + mrow] = f2bf(acc[f][r]);
        }
    }
}

// ---------------------------------------------------------------------------
// K3: CSR scatter. One wave per atom i: y[i,:] = sum_p alpha[p] * v[idx_j[p],:]
// j/alpha are wave-uniform (p from readfirstlane'd bounds) -> scalar loads,
// no shfl, no LDS, no atomics. Lane l holds features 2l,2l+1 (one dword of
// bf16 pair per lane = 256 B coalesced row gather). y written exactly once.
// ---------------------------------------------------------------------------
__global__ __launch_bounds__(256) void scatter_csr(const ushort* __restrict__ v,
                                                   const float* __restrict__ alpha,
                                                   const int* __restrict__ idx_j,
                                                   const int* __restrict__ rowptr,
                                                   float* __restrict__ y) {
    const int lane = threadIdx.x & 63;
    const int wave = blockIdx.x * 4 + (threadIdx.x >> 6);
    if (wave >= N_ATOMS) return;

    const int start = __builtin_amdgcn_readfirstlane(rowptr[wave]);
    const int end   = __builtin_amdgcn_readfirstlane(rowptr[wave + 1]);

    float ax = 0.f, ay = 0.f;
    const ushort* vb = v + 2 * lane;
#pragma unroll 4
    for (int p = start; p < end; ++p) {
        const int   j = idx_j[p];      // uniform -> s_load / broadcast
        const float a = alpha[p];
        const unsigned vv = *(const unsigned*)(vb + (long)j * FDIM);
        const float lo = __uint_as_float(vv << 16);
        const float hi = __uint_as_float(vv & 0xffff0000u);
        ax += a * lo;
        ay += a * hi;
    }
    *(float2*)(y + (long)wave * FDIM + 2 * lane) = make_float2(ax, ay);
}

extern "C" void kernel_launch(void* const* d_in, const int* in_sizes, int n_in,
                              void* d_out, int out_size, void* d_ws, size_t ws_size,
                              hipStream_t stream) {
    const float* x     = (const float*)d_in[0];
    const float* alpha = (const float*)d_in[1];
    const int*   idx_i = (const int*)d_in[2];   // int32 per harness contract
    const int*   idx_j = (const int*)d_in[3];
    const float* W     = (const float*)d_in[4];
    float* y = (float*)d_out;

    ushort* v      = (ushort*)d_ws;                                    // 12.8 MB
    int*    rowptr = (int*)((char*)d_ws + (size_t)N_ATOMS * FDIM * 2); // 200 KB

    build_rowptr<<<(N_ATOMS + 1 + 255) / 256, 256, 0, stream>>>(idx_i, rowptr);
    gemm_xwt_bf16<<<(N_ATOMS + 63) / 64, 256, 0, stream>>>(x, W, v);
    scatter_csr<<<(N_ATOMS + 3) / 4, 256, 0, stream>>>(v, alpha, idx_j, rowptr, y);
}